// Round 3
// baseline (11206.264 us; speedup 1.0000x reference)
//
#include <hip/hip_runtime.h>
#include <stdint.h>

#define TSTEPS 512
#define NB 512
#define ND 512
#define NH 512

#define WPG 32            // waves per group = 8 WGs * 4 waves
#define NGROUPS 32
#define CTR_STRIDE 64     // uints (256B spacing)

typedef _Float16 half8 __attribute__((ext_vector_type(8)));
typedef float float4v __attribute__((ext_vector_type(4)));

__device__ __forceinline__ float fast_tanh(float x) {
  // tanh(x) = 1 - 2/(e^{2x}+1); saturates correctly at +/-inf, no NaN.
  float e = __expf(2.0f * x);
  return 1.0f - 2.0f * __builtin_amdgcn_rcpf(e + 1.0f);
}

// Persistent RNN kernel. Grid = 256 WGs x 256 threads (4 waves), 1 WG/CU
// (regular launch; co-residency is structural: grid=256 <= 1 block/CU * 256 CU,
//  so the CP dispatches every block at t=0 and no block waits on retirement).
// Row-group g = bid&31 owns batch rows [16g,16g+16); col-WG c = bid>>5 owns
// hidden cols [64c, 64c+64). Group members share bid%8 -> same XCD (heuristic).
// Waves K-split (128 K each) over both the D (input) and H (recurrent) dots;
// partials reduced through LDS. W_ih/W_hh slices live entirely in VGPRs as
// pre-built MFMA B-fragments. h ping-pongs through d_ws as fp16; sync is a
// per-group monotonic counter (release add / relaxed sc1 poll).
__global__ void __launch_bounds__(256, 1)
rnn_persistent(const float* __restrict__ x,     // [T,B,D]
               const float* __restrict__ Wih,   // [H,D]
               const float* __restrict__ Whh,   // [H,H]
               const float* __restrict__ bih,   // [H]
               const float* __restrict__ bhh,   // [H]
               float* __restrict__ out,         // [B,H]
               _Float16* __restrict__ hbuf,     // ws: [2][B][H] fp16
               unsigned* __restrict__ counters) // ws: [NGROUPS*CTR_STRIDE]
{
  __shared__ float red[4][16][68];   // padded: 2-way banks max (free)

  const int bid  = blockIdx.x;
  const int grp  = bid & 31;
  const int cwg  = bid >> 5;              // 0..7
  const int wave = threadIdx.x >> 6;      // 0..3
  const int lane = threadIdx.x & 63;
  const int m    = lane & 15;
  const int quad = lane >> 4;

  const int R     = grp * 16;             // batch-row base
  const int C0    = cwg * 64;             // hidden-col base
  const int kbase = wave * 128;           // this wave's K slice

  unsigned* ctr = counters + grp * CTR_STRIDE;

  // ---- preload W fragments (MFMA B-operand layout) into registers ----
  // B[k][n], n = lane&15 (+tile*16), k = quad*8 + j (+kk*32 + kbase)
  half8 wih_f[4][4];  // [kk][tile]
  half8 whh_f[4][4];
  #pragma unroll
  for (int tile = 0; tile < 4; ++tile) {
    const int n = C0 + tile * 16 + m;
    const float* wr_ih = Wih + (size_t)n * ND;
    const float* wr_hh = Whh + (size_t)n * NH;
    #pragma unroll
    for (int kk = 0; kk < 4; ++kk) {
      const int k0 = kbase + kk * 32 + quad * 8;
      half8 a, b;
      #pragma unroll
      for (int j = 0; j < 8; ++j) {
        a[j] = (_Float16)wr_ih[k0 + j];   // RTNE cast: rel err 2^-11
        b[j] = (_Float16)wr_hh[k0 + j];
      }
      wih_f[kk][tile] = a;
      whh_f[kk][tile] = b;
    }
  }

  // After reduction this wave owns cols [C0+wave*16, +16), rows R..R+16.
  const int mycol = C0 + wave * 16 + m;
  const float bias = bih[mycol] + bhh[mycol];
  const int myrow = R + m;                // A-operand row (m = lane&15)
  const int orow  = quad * 4;             // C/D row base (row = quad*4 + reg)

  for (int t = 0; t < TSTEPS; ++t) {
    float4v acc[4];
    #pragma unroll
    for (int tile = 0; tile < 4; ++tile) acc[tile] = (float4v){0.f, 0.f, 0.f, 0.f};

    // ---- x-part: on-the-fly input projection (overlaps peers' publish) ----
    const float* xrow = x + ((size_t)t * NB + myrow) * ND + kbase + quad * 8;
    float4v xv[4][2];
    #pragma unroll
    for (int kk = 0; kk < 4; ++kk) {
      xv[kk][0] = *(const float4v*)(xrow + kk * 32);
      xv[kk][1] = *(const float4v*)(xrow + kk * 32 + 4);
    }
    #pragma unroll
    for (int kk = 0; kk < 4; ++kk) {
      half8 a;
      #pragma unroll
      for (int j = 0; j < 4; ++j) {
        a[j]     = (_Float16)xv[kk][0][j];
        a[j + 4] = (_Float16)xv[kk][1][j];
      }
      #pragma unroll
      for (int tile = 0; tile < 4; ++tile)
        acc[tile] = __builtin_amdgcn_mfma_f32_16x16x32_f16(a, wih_f[kk][tile], acc[tile], 0, 0, 0);
    }

    // ---- wait for h_t (all 32 waves of the group published), then h-part ----
    if (t > 0) {
      const unsigned tgt = (unsigned)(WPG * t);
      unsigned c;
      while ((c = __hip_atomic_load(ctr, __ATOMIC_RELAXED, __HIP_MEMORY_SCOPE_AGENT)) < tgt)
        __builtin_amdgcn_s_sleep(1);
      // (c >> 31) == 0 at runtime (counter < 2^31) but opaque to the compiler:
      // forces the h loads to be data-dependent on the successful poll so they
      // cannot be hoisted above it. HW-side: producer's agent-scope release RMW
      // writes back L2 before bumping ctr; sc1 relaxed loads read at the
      // coherence point, and are issued only after the poll branch resolves.
      const _Float16* hb = hbuf + (size_t)(t & 1) * NB * NH + (size_t)(c >> 31);
      const unsigned long long* hrow =
          (const unsigned long long*)(hb + (size_t)myrow * NH + kbase + quad * 8);
      #pragma unroll
      for (int kk = 0; kk < 4; ++kk) {
        // agent-scope relaxed loads: served at the device coherence point,
        // no cache-invalidate storm (keeps x stream L2-resident).
        unsigned long long lo = __hip_atomic_load(hrow + kk * 8,     __ATOMIC_RELAXED, __HIP_MEMORY_SCOPE_AGENT);
        unsigned long long hi = __hip_atomic_load(hrow + kk * 8 + 1, __ATOMIC_RELAXED, __HIP_MEMORY_SCOPE_AGENT);
        union { unsigned long long u[2]; half8 h; } cv;
        cv.u[0] = lo; cv.u[1] = hi;
        #pragma unroll
        for (int tile = 0; tile < 4; ++tile)
          acc[tile] = __builtin_amdgcn_mfma_f32_16x16x32_f16(cv.h, whh_f[kk][tile], acc[tile], 0, 0, 0);
      }
    }

    // ---- cross-wave K reduction via LDS ----
    #pragma unroll
    for (int tile = 0; tile < 4; ++tile) {
      #pragma unroll
      for (int r = 0; r < 4; ++r)
        red[wave][orow + r][tile * 16 + m] = acc[tile][r];
    }
    __syncthreads();
    // (write(t+1) vs read(t) hazard is covered by the group counter: a wave
    //  cannot pass poll(32*(t+1)) until every local wave released t, and the
    //  release is program-ordered after these reads.)
    float vals[4];
    #pragma unroll
    for (int r = 0; r < 4; ++r) {
      float s = bias
              + red[0][orow + r][wave * 16 + m]
              + red[1][orow + r][wave * 16 + m]
              + red[2][orow + r][wave * 16 + m]
              + red[3][orow + r][wave * 16 + m];
      vals[r] = fast_tanh(s);
    }

    // ---- publish h_{t+1} (fp16 ping-pong) or final output (fp32) ----
    if (t < TSTEPS - 1) {
      _Float16* hb1 = hbuf + (size_t)((t + 1) & 1) * NB * NH;
      #pragma unroll
      for (int r = 0; r < 4; ++r)
        hb1[(size_t)(R + orow + r) * NH + mycol] = (_Float16)vals[r];
      if (lane == 0)   // release: drains this wave's stores + L2 writeback first
        __hip_atomic_fetch_add(ctr, 1u, __ATOMIC_RELEASE, __HIP_MEMORY_SCOPE_AGENT);
    } else {
      #pragma unroll
      for (int r = 0; r < 4; ++r)
        out[(size_t)(R + orow + r) * NH + mycol] = vals[r];
    }
  }
}

extern "C" void kernel_launch(void* const* d_in, const int* in_sizes, int n_in,
                              void* d_out, int out_size, void* d_ws, size_t ws_size,
                              hipStream_t stream) {
  const float* x   = (const float*)d_in[0];
  const float* Wih = (const float*)d_in[1];
  const float* Whh = (const float*)d_in[2];
  const float* bih = (const float*)d_in[3];
  const float* bhh = (const float*)d_in[4];
  // d_in[5] = hidden_size scalar (unused; H fixed at 512)
  float* out = (float*)d_out;

  _Float16* hbuf     = (_Float16*)d_ws;                                  // 1 MB
  unsigned* counters = (unsigned*)((char*)d_ws + (size_t)2 * NB * NH * 2);

  (void)hipMemsetAsync(counters, 0, NGROUPS * CTR_STRIDE * sizeof(unsigned), stream);

  rnn_persistent<<<dim3(256), dim3(256), 0, stream>>>(
      x, Wih, Whh, bih, bhh, out, hbuf, counters);
}